// Round 5
// baseline (325.108 us; speedup 1.0000x reference)
//
#include <hip/hip_runtime.h>
#include <math.h>

#define Bq 4
#define Hq 512
#define Nq 64
#define Lq 2048
#define PARAM (Hq*Nq)   // 32768
#define T 64
#define NC (Lq/T)       // 32 chunks
#define NCOL 256        // 2 dirs * Bq * NC columns per h

// ---------------------------------------------------------------------------
// Phase 1: per-(h,n) parameter prep + global power table.
//   pw[h][d][n] = (Re w^d, Im w^d) for d = 0..64, float2 interleaved.
// ---------------------------------------------------------------------------
__global__ void prep_kernel(const float* __restrict__ log_dt,
                            const float* __restrict__ log_A_real,
                            const float* __restrict__ A_imag,
                            const float* __restrict__ B_re, const float* __restrict__ B_im,
                            const float* __restrict__ C_re, const float* __restrict__ C_im,
                            float* __restrict__ a0, float* __restrict__ b0,
                            float* __restrict__ a1, float* __restrict__ b1,
                            float* __restrict__ pw) {
    int idx = blockIdx.x * blockDim.x + threadIdx.x;
    if (idx >= PARAM) return;
    int h = idx >> 6, n = idx & 63;
    float dt = expf(log_dt[h]);
    float Ar = -expf(log_A_real[idx]);
    float Ai = A_imag[idx];
    float er = expf(Ar * dt);
    float wr = er * cosf(Ai * dt);
    float wi = er * sinf(Ai * dt);
    float mr = wr - 1.0f, mi = wi;
    float den = Ar * Ar + Ai * Ai;
    float qr = (mr * Ar + mi * Ai) / den;
    float qi = (mi * Ar - mr * Ai) / den;
    float Br = B_re[idx], Bi = B_im[idx];
    float dBr = Br * qr - Bi * qi;
    float dBi = Br * qi + Bi * qr;
    float cr = C_re[idx], ci = C_im[idx];
    a0[idx] =  2.0f * (cr * dBr - ci * dBi);
    b0[idx] = -2.0f * (cr * dBi + ci * dBr);
    cr = C_re[PARAM + idx]; ci = C_im[PARAM + idx];
    a1[idx] =  2.0f * (cr * dBr - ci * dBi);
    b1[idx] = -2.0f * (cr * dBi + ci * dBr);
    float c = 1.f, s = 0.f;
    float* base = pw + (size_t)h * 65 * 128 + 2 * n;
    for (int d = 0; d <= 64; ++d) {
        *(float2*)(base + (size_t)d * 128) = float2{c, s};
        float nc = c * wr - s * wi;
        float ns = c * wi + s * wr;
        c = nc; s = ns;
    }
}

// ---------------------------------------------------------------------------
// Phase 1b: Toeplitz taps k[h][dir][d] = sum_n a*Re(w^d) + b*Im(w^d).
// ---------------------------------------------------------------------------
__global__ __launch_bounds__(128)
void ktap_kernel(const float* __restrict__ pw,
                 const float* __restrict__ a0, const float* __restrict__ b0,
                 const float* __restrict__ a1, const float* __restrict__ b1,
                 float* __restrict__ kt) {
    int h = blockIdx.x;
    int t = threadIdx.x;
    int dir = t >> 6, d = t & 63;
    const float* aa = dir ? a1 : a0;
    const float* bb = dir ? b1 : b0;
    const float* row = pw + (size_t)(h * 65 + d) * 128;
    float acc = 0.f;
    for (int n = 0; n < 64; ++n) {
        float2 v = *(const float2*)(row + 2 * n);
        acc = fmaf(aa[h * 64 + n], v.x, acc);
        acc = fmaf(bb[h * 64 + n], v.y, acc);
    }
    kt[((size_t)h * 2 + dir) * 64 + d] = acc;
}

// ---------------------------------------------------------------------------
// Phase 2: LayerNorm over channel dim H for each (b,l).  (unchanged)
// ---------------------------------------------------------------------------
__global__ __launch_bounds__(256)
void ln_kernel(const float* __restrict__ x, const float* __restrict__ lnw,
               const float* __restrict__ lnb, float* __restrict__ z) {
    int blk = blockIdx.x;
    int b  = blk / (Lq / 16);
    int l0 = (blk % (Lq / 16)) * 16;
    int tx = threadIdx.x & 15;
    int ty = threadIdx.x >> 4;
    const float* xb = x + (size_t)b * Hq * Lq;
    float s = 0.f, s2 = 0.f;
    for (int h = ty; h < Hq; h += 16) {
        float v = xb[h * Lq + l0 + tx];
        s += v; s2 += v * v;
    }
    __shared__ float rs_[16][17], r2_[16][17], mu_s[16], sg_s[16];
    rs_[ty][tx] = s; r2_[ty][tx] = s2;
    __syncthreads();
    if (ty == 0) {
        float a = 0.f, c = 0.f;
        #pragma unroll
        for (int i = 0; i < 16; ++i) { a += rs_[i][tx]; c += r2_[i][tx]; }
        float mu = a * (1.0f / Hq);
        float var = c * (1.0f / Hq) - mu * mu;
        mu_s[tx] = mu;
        sg_s[tx] = rsqrtf(var + 1e-5f);
    }
    __syncthreads();
    float mu = mu_s[tx], rs = sg_s[tx];
    float* zb = z + (size_t)b * Hq * Lq;
    for (int h = ty; h < Hq; h += 16) {
        float v = xb[h * Lq + l0 + tx];
        zb[h * Lq + l0 + tx] = (v - mu) * rs * lnw[h] + lnb[h];
    }
}

// ---------------------------------------------------------------------------
// delta GEMM (unchanged)
// ---------------------------------------------------------------------------
__global__ __launch_bounds__(256, 6)
void delta_kernel(const float* __restrict__ z, const float* __restrict__ pw,
                  float* __restrict__ buf) {
    __shared__ float Bs[64][68];
    int h = blockIdx.x, ct = blockIdx.y;
    int t = threadIdx.x;
    int dir = ct >> 1;
    int cc = t & 31, rb = (t >> 5) & 1, jg = t >> 6;
    int b = (ct & 1) * 2 + rb;
    const float* zb = z + ((size_t)b * Hq + h) * Lq;
    if (dir == 0) {
        #pragma unroll
        for (int f = 0; f < 4; ++f) {
            float4 v = *(const float4*)(zb + cc * 64 + 16 * jg + 4 * f);
            Bs[16*jg+4*f+0][rb*32+cc] = v.x;
            Bs[16*jg+4*f+1][rb*32+cc] = v.y;
            Bs[16*jg+4*f+2][rb*32+cc] = v.z;
            Bs[16*jg+4*f+3][rb*32+cc] = v.w;
        }
    } else {
        #pragma unroll
        for (int f = 0; f < 4; ++f) {
            float4 v = *(const float4*)(zb + 2044 - cc * 64 - 16 * jg - 4 * f);
            Bs[16*jg+4*f+3][rb*32+cc] = v.x;
            Bs[16*jg+4*f+2][rb*32+cc] = v.y;
            Bs[16*jg+4*f+1][rb*32+cc] = v.z;
            Bs[16*jg+4*f+0][rb*32+cc] = v.w;
        }
    }
    __syncthreads();
    int tx = t & 15, ty = t >> 4;
    float aR[4][4] = {}, aI[4][4] = {};
    const float* pwh = pw + (size_t)h * 65 * 128;
    #pragma unroll 4
    for (int kk = 0; kk < 64; ++kk) {
        int d = 63 - kk;
        const float4* pr = (const float4*)(pwh + (size_t)d * 128 + 8 * tx);
        float4 p0 = pr[0], p1 = pr[1];
        float4 bv = *(const float4*)&Bs[kk][4 * ty];
        float pc[4] = {p0.x, p0.z, p1.x, p1.z};
        float ps[4] = {p0.y, p0.w, p1.y, p1.w};
        #pragma unroll
        for (int rr = 0; rr < 4; ++rr) {
            #pragma unroll
            for (int q = 0; q < 4; ++q) {
                aR[rr][q] = fmaf(pc[rr], (&bv.x)[q], aR[rr][q]);
                aI[rr][q] = fmaf(ps[rr], (&bv.x)[q], aI[rr][q]);
            }
        }
    }
    #pragma unroll
    for (int q = 0; q < 4; ++q) {
        int colg = ct * 64 + 4 * ty + q;
        float* dst = buf + ((size_t)h * NCOL + colg) * 128 + 8 * tx;
        float4 v1, v2;
        v1.x = aR[0][q]; v1.y = aI[0][q]; v1.z = aR[1][q]; v1.w = aI[1][q];
        v2.x = aR[2][q]; v2.y = aI[2][q]; v2.z = aR[3][q]; v2.w = aI[3][q];
        *(float4*)dst = v1; *(float4*)(dst + 4) = v2;
    }
}

// ---------------------------------------------------------------------------
// inter-chunk scan (unchanged)
// ---------------------------------------------------------------------------
__global__ __launch_bounds__(256)
void cscan_kernel(const float* __restrict__ pw, float* __restrict__ buf) {
    int e = blockIdx.x * 4 + (threadIdx.x >> 6);
    int n = threadIdx.x & 63;
    int h = e >> 3, dir = (e >> 2) & 1, b = e & 3;
    float2 t64 = *(const float2*)(pw + (size_t)(h * 65 + 64) * 128 + 2 * n);
    float tc = t64.x, ts = t64.y;
    float sr = 0.f, si = 0.f;
    float2* p = (float2*)(buf + ((size_t)h * NCOL + dir * 128 + b * 32) * 128) + n;
    float2 d = p[0];
    for (int c = 0; c < NC; ++c) {
        float2 dn;
        if (c + 1 < NC) dn = p[(c + 1) * 64];
        float2 s; s.x = sr; s.y = si;
        p[c * 64] = s;
        float nr = fmaf(tc, sr, fmaf(-ts, si, d.x));
        float ni = fmaf(ts, sr, fmaf(tc, si, d.y));
        sr = nr; si = ni; d = dn;
    }
}

// ---------------------------------------------------------------------------
// Fused bidirectional Y GEMM + activation, physical coordinates.
// Block = (h, b): 64 rows (l within chunk) x 32 cols (chunks). 10 phases:
//   p=0,1 : merged Toeplitz A[i][j] = (j<=i ? k0[i-j] : k1[j-i-1]), B = z
//   p=2..5: G0 rows (w^{i+1}),   B = S0 scan cols  (dir0 state)
//   p=6..9: G1 rows (w^{63-i}),  B = S1 scan col 31-cc (dir1 state, reversed)
// Epilogue: u = gelu(acc + D*z) written directly in physical order.
// ---------------------------------------------------------------------------
__global__ __launch_bounds__(256, 8)
void yact_kernel(const float* __restrict__ z, const float* __restrict__ pw,
                 const float* __restrict__ a0, const float* __restrict__ b0,
                 const float* __restrict__ a1, const float* __restrict__ b1,
                 const float* __restrict__ kt, const float* __restrict__ buf,
                 const float* __restrict__ Dv, float* __restrict__ u) {
    __shared__ float As[32][68];
    __shared__ float Bs[32][36];
    __shared__ float ks0[64], ks1[64], as0_[64], bs0_[64], as1_[64], bs1_[64];
    int h = blockIdx.x, b = blockIdx.y;
    int t = threadIdx.x;
    if (t < 64) {
        ks0[t]  = kt[((size_t)h * 2 + 0) * 64 + t];
        ks1[t]  = kt[((size_t)h * 2 + 1) * 64 + t];
        as0_[t] = a0[h * 64 + t]; bs0_[t] = b0[h * 64 + t];
        as1_[t] = a1[h * 64 + t]; bs1_[t] = b1[h * 64 + t];
    }
    int tx = t & 15, ty = t >> 4;          // microtile: rows 4tx+ii, cols 2ty+q
    int si = t & 63, kkg = t >> 6;         // As staging: row si, kk = 8kkg+q
    int cc = t & 31, kg = t >> 5;          // Bs staging: col cc, kk = 4kg+e
    const float* zb   = z + ((size_t)b * Hq + h) * Lq;
    const float* bufh = buf + (size_t)h * NCOL * 128;
    const float* prow0 = pw + (size_t)(h * 65 + si + 1) * 128;   // w^{i+1}
    const float* prow1 = pw + (size_t)(h * 65 + 63 - si) * 128;  // w^{63-i}
    float acc[4][2] = {};
    __syncthreads();
    for (int p = 0; p < 10; ++p) {
        // ---- stage As[kk][i] ----
        if (p < 2) {
            #pragma unroll
            for (int q = 0; q < 8; ++q) {
                int kk = 8 * kkg + q;
                int j = 32 * p + kk;
                int d = si - j;
                As[kk][si] = (d >= 0) ? ks0[d] : ks1[-d - 1];
            }
        } else if (p < 6) {
            #pragma unroll
            for (int q = 0; q < 8; ++q) {
                int kk = 8 * kkg + q;
                int m = 32 * (p - 2) + kk;
                int n = m >> 1;
                float2 v = *(const float2*)(prow0 + 2 * n);
                As[kk][si] = ((m & 1) == 0) ? fmaf(as0_[n], v.x, bs0_[n] * v.y)
                                            : fmaf(bs0_[n], v.x, -as0_[n] * v.y);
            }
        } else {
            #pragma unroll
            for (int q = 0; q < 8; ++q) {
                int kk = 8 * kkg + q;
                int m = 32 * (p - 6) + kk;
                int n = m >> 1;
                float2 v = *(const float2*)(prow1 + 2 * n);
                As[kk][si] = ((m & 1) == 0) ? fmaf(as1_[n], v.x, bs1_[n] * v.y)
                                            : fmaf(bs1_[n], v.x, -as1_[n] * v.y);
            }
        }
        // ---- stage Bs[kk][col] ----
        if (p < 2) {
            float4 v = *(const float4*)(zb + cc * 64 + 32 * p + 4 * kg);
            Bs[4*kg+0][cc] = v.x; Bs[4*kg+1][cc] = v.y;
            Bs[4*kg+2][cc] = v.z; Bs[4*kg+3][cc] = v.w;
        } else if (p < 6) {
            int colg = b * 32 + cc;
            float4 v = *(const float4*)(bufh + (size_t)colg * 128 + 32 * (p - 2) + 4 * kg);
            Bs[4*kg+0][cc] = v.x; Bs[4*kg+1][cc] = v.y;
            Bs[4*kg+2][cc] = v.z; Bs[4*kg+3][cc] = v.w;
        } else {
            int colg = 128 + b * 32 + (31 - cc);
            float4 v = *(const float4*)(bufh + (size_t)colg * 128 + 32 * (p - 6) + 4 * kg);
            Bs[4*kg+0][cc] = v.x; Bs[4*kg+1][cc] = v.y;
            Bs[4*kg+2][cc] = v.z; Bs[4*kg+3][cc] = v.w;
        }
        __syncthreads();
        #pragma unroll 8
        for (int kk = 0; kk < 32; ++kk) {
            float4 av = *(const float4*)&As[kk][4 * tx];
            float2 bv = *(const float2*)&Bs[kk][2 * ty];
            #pragma unroll
            for (int ii = 0; ii < 4; ++ii) {
                float a = (&av.x)[ii];
                acc[ii][0] = fmaf(a, bv.x, acc[ii][0]);
                acc[ii][1] = fmaf(a, bv.y, acc[ii][1]);
            }
        }
        __syncthreads();
    }
    float dv = Dv[h];
    #pragma unroll
    for (int q = 0; q < 2; ++q) {
        int cc2 = 2 * ty + q;
        size_t base = ((size_t)b * Hq + h) * Lq + cc2 * 64 + 4 * tx;
        float4 zr = *(const float4*)(z + base);
        float vv[4];
        vv[0] = acc[0][q] + dv * zr.x;
        vv[1] = acc[1][q] + dv * zr.y;
        vv[2] = acc[2][q] + dv * zr.z;
        vv[3] = acc[3][q] + dv * zr.w;
        #pragma unroll
        for (int i = 0; i < 4; ++i) {
            float v = vv[i];
            float tt = tanhf(0.7978845608028654f * (v + 0.044715f * v * v * v));
            vv[i] = 0.5f * v * (1.0f + tt);
        }
        float4 r; r.x = vv[0]; r.y = vv[1]; r.z = vv[2]; r.w = vv[3];
        *(float4*)(u + base) = r;
    }
}

// ---------------------------------------------------------------------------
// Phase 5: out = bias + x + W@u. (unchanged from round 4)
// ---------------------------------------------------------------------------
__global__ __launch_bounds__(512, 4)
void gemm_kernel(const float* __restrict__ u, const float* __restrict__ W,
                 const float* __restrict__ bias, const float* __restrict__ x,
                 float* __restrict__ out) {
    int l0 = blockIdx.x * 64;
    int o0 = blockIdx.y * 128;
    int b  = blockIdx.z;
    int tid = threadIdx.x;
    __shared__ float Ws[2][32][132];
    __shared__ float Us[2][32][68];
    const float* ub = u + (size_t)b * Hq * Lq;
    float acc[4][4] = {};
    int wo = tid >> 4, wl = tid & 15;
    int sj = tid & 31, so = tid >> 5;
    int sl = tid & 63, sk = tid >> 6;
    float wreg[8], ureg[4];
    #pragma unroll
    for (int r = 0; r < 8; ++r) wreg[r] = W[(size_t)(o0 + so + 16*r) * Hq + sj];
    #pragma unroll
    for (int r = 0; r < 4; ++r) ureg[r] = ub[(size_t)(4*sk + r) * Lq + l0 + sl];
    #pragma unroll
    for (int r = 0; r < 8; ++r) Ws[0][sj][so + 16*r] = wreg[r];
    #pragma unroll
    for (int r = 0; r < 4; ++r) Us[0][4*sk + r][sl] = ureg[r];
    __syncthreads();
    for (int t = 0; t < Hq / 32; ++t) {
        int cur = t & 1;
        if (t < 15) {
            int k0 = (t + 1) * 32;
            #pragma unroll
            for (int r = 0; r < 8; ++r)
                wreg[r] = W[(size_t)(o0 + so + 16*r) * Hq + k0 + sj];
            #pragma unroll
            for (int r = 0; r < 4; ++r)
                ureg[r] = ub[(size_t)(k0 + 4*sk + r) * Lq + l0 + sl];
        }
        #pragma unroll 8
        for (int j = 0; j < 32; ++j) {
            float4 av = *(const float4*)&Ws[cur][j][4 * wo];
            float4 bv = *(const float4*)&Us[cur][j][4 * wl];
            #pragma unroll
            for (int io = 0; io < 4; ++io) {
                float a = (&av.x)[io];
                acc[io][0] = fmaf(a, bv.x, acc[io][0]);
                acc[io][1] = fmaf(a, bv.y, acc[io][1]);
                acc[io][2] = fmaf(a, bv.z, acc[io][2]);
                acc[io][3] = fmaf(a, bv.w, acc[io][3]);
            }
        }
        if (t < 15) {
            int nxt = cur ^ 1;
            #pragma unroll
            for (int r = 0; r < 8; ++r) Ws[nxt][sj][so + 16*r] = wreg[r];
            #pragma unroll
            for (int r = 0; r < 4; ++r) Us[nxt][4*sk + r][sl] = ureg[r];
        }
        __syncthreads();
    }
    #pragma unroll
    for (int io = 0; io < 4; ++io) {
        int o = o0 + 4 * wo + io;
        float bo = bias[o];
        size_t base = ((size_t)b * Hq + o) * Lq + l0 + 4 * wl;
        const float4 xr = *(const float4*)(x + base);
        float4 r;
        r.x = acc[io][0] + bo + xr.x;
        r.y = acc[io][1] + bo + xr.y;
        r.z = acc[io][2] + bo + xr.z;
        r.w = acc[io][3] + bo + xr.w;
        *(float4*)(out + base) = r;
    }
}

// ---------------------------------------------------------------------------
extern "C" void kernel_launch(void* const* d_in, const int* in_sizes, int n_in,
                              void* d_out, int out_size, void* d_ws, size_t ws_size,
                              hipStream_t stream) {
    (void)in_sizes; (void)n_in; (void)out_size; (void)ws_size;
    const float* x          = (const float*)d_in[0];
    const float* ln_w       = (const float*)d_in[1];
    const float* ln_b       = (const float*)d_in[2];
    const float* log_dt     = (const float*)d_in[3];
    const float* log_A_real = (const float*)d_in[4];
    const float* A_imag     = (const float*)d_in[5];
    const float* B_re       = (const float*)d_in[6];
    const float* B_im       = (const float*)d_in[7];
    const float* C_re       = (const float*)d_in[8];
    const float* C_im       = (const float*)d_in[9];
    const float* Dv         = (const float*)d_in[10];
    const float* W          = (const float*)d_in[11];
    const float* b_out      = (const float*)d_in[12];
    float* out = (float*)d_out;
    float* ws  = (float*)d_ws;

    const size_t BHL = (size_t)Bq * Hq * Lq;
    float* a0  = ws;
    float* b0  = ws + (size_t)PARAM;
    float* a1  = ws + 2 * (size_t)PARAM;
    float* b1  = ws + 3 * (size_t)PARAM;
    float* kt  = ws + 4 * (size_t)PARAM;
    float* pw  = ws + 6 * (size_t)PARAM;           // 512*65*128 = 130*PARAM
    float* z   = ws + 136 * (size_t)PARAM;
    float* u   = z  + BHL;
    float* buf = u + BHL;                          // 512*256*128 = 67 MB

    prep_kernel<<<PARAM / 256, 256, 0, stream>>>(log_dt, log_A_real, A_imag,
                                                 B_re, B_im, C_re, C_im,
                                                 a0, b0, a1, b1, pw);
    ln_kernel<<<Bq * (Lq / 16), 256, 0, stream>>>(x, ln_w, ln_b, z);
    ktap_kernel<<<Hq, 128, 0, stream>>>(pw, a0, b0, a1, b1, kt);
    delta_kernel<<<dim3(Hq, 4), 256, 0, stream>>>(z, pw, buf);
    cscan_kernel<<<Bq * Hq * 2 / 4, 256, 0, stream>>>(pw, buf);
    yact_kernel<<<dim3(Hq, Bq), 256, 0, stream>>>(z, pw, a0, b0, a1, b1,
                                                  kt, buf, Dv, u);
    gemm_kernel<<<dim3(Lq / 64, Hq / 128, Bq), 512, 0, stream>>>(u, W, b_out, x, out);
}

// Round 6
// 316.310 us; speedup vs baseline: 1.0278x; 1.0278x over previous
//
#include <hip/hip_runtime.h>
#include <math.h>

#define Bq 4
#define Hq 512
#define Nq 64
#define Lq 2048
#define PARAM (Hq*Nq)   // 32768
#define T 64
#define NC (Lq/T)       // 32 chunks
#define NCOL 256        // 2 dirs * Bq * NC columns per h

// ---------------------------------------------------------------------------
// Phase 1: per-(h,n) parameter prep + power tables (two layouts).
//   pw [h][d][n]: (Re w^d, Im w^d), d=0..64   (delta/ktap/cscan: row-d access)
//   pwT[h][n][d]: same values transposed      (yact: lane-along-d coalesced)
// ---------------------------------------------------------------------------
__global__ void prep_kernel(const float* __restrict__ log_dt,
                            const float* __restrict__ log_A_real,
                            const float* __restrict__ A_imag,
                            const float* __restrict__ B_re, const float* __restrict__ B_im,
                            const float* __restrict__ C_re, const float* __restrict__ C_im,
                            float* __restrict__ a0, float* __restrict__ b0,
                            float* __restrict__ a1, float* __restrict__ b1,
                            float* __restrict__ pw, float* __restrict__ pwT) {
    int idx = blockIdx.x * blockDim.x + threadIdx.x;
    if (idx >= PARAM) return;
    int h = idx >> 6, n = idx & 63;
    float dt = expf(log_dt[h]);
    float Ar = -expf(log_A_real[idx]);
    float Ai = A_imag[idx];
    float er = expf(Ar * dt);
    float wr = er * cosf(Ai * dt);
    float wi = er * sinf(Ai * dt);
    float mr = wr - 1.0f, mi = wi;
    float den = Ar * Ar + Ai * Ai;
    float qr = (mr * Ar + mi * Ai) / den;
    float qi = (mi * Ar - mr * Ai) / den;
    float Br = B_re[idx], Bi = B_im[idx];
    float dBr = Br * qr - Bi * qi;
    float dBi = Br * qi + Bi * qr;
    float cr = C_re[idx], ci = C_im[idx];
    a0[idx] =  2.0f * (cr * dBr - ci * dBi);
    b0[idx] = -2.0f * (cr * dBi + ci * dBr);
    cr = C_re[PARAM + idx]; ci = C_im[PARAM + idx];
    a1[idx] =  2.0f * (cr * dBr - ci * dBi);
    b1[idx] = -2.0f * (cr * dBi + ci * dBr);
    float c = 1.f, s = 0.f;
    float* base  = pw  + (size_t)h * 65 * 128 + 2 * n;
    float* baseT = pwT + (size_t)(h * 64 + n) * 132;
    for (int d = 0; d <= 64; ++d) {
        *(float2*)(base + (size_t)d * 128) = float2{c, s};
        *(float2*)(baseT + 2 * d)          = float2{c, s};
        float nc = c * wr - s * wi;
        float ns = c * wi + s * wr;
        c = nc; s = ns;
    }
}

// ---------------------------------------------------------------------------
// Phase 1b: Toeplitz taps k[h][dir][d] = sum_n a*Re(w^d) + b*Im(w^d).
// ---------------------------------------------------------------------------
__global__ __launch_bounds__(128)
void ktap_kernel(const float* __restrict__ pw,
                 const float* __restrict__ a0, const float* __restrict__ b0,
                 const float* __restrict__ a1, const float* __restrict__ b1,
                 float* __restrict__ kt) {
    int h = blockIdx.x;
    int t = threadIdx.x;
    int dir = t >> 6, d = t & 63;
    const float* aa = dir ? a1 : a0;
    const float* bb = dir ? b1 : b0;
    const float* row = pw + (size_t)(h * 65 + d) * 128;
    float acc = 0.f;
    for (int n = 0; n < 64; ++n) {
        float2 v = *(const float2*)(row + 2 * n);
        acc = fmaf(aa[h * 64 + n], v.x, acc);
        acc = fmaf(bb[h * 64 + n], v.y, acc);
    }
    kt[((size_t)h * 2 + dir) * 64 + d] = acc;
}

// ---------------------------------------------------------------------------
// Phase 2: LayerNorm over channel dim H for each (b,l).  (unchanged)
// ---------------------------------------------------------------------------
__global__ __launch_bounds__(256)
void ln_kernel(const float* __restrict__ x, const float* __restrict__ lnw,
               const float* __restrict__ lnb, float* __restrict__ z) {
    int blk = blockIdx.x;
    int b  = blk / (Lq / 16);
    int l0 = (blk % (Lq / 16)) * 16;
    int tx = threadIdx.x & 15;
    int ty = threadIdx.x >> 4;
    const float* xb = x + (size_t)b * Hq * Lq;
    float s = 0.f, s2 = 0.f;
    for (int h = ty; h < Hq; h += 16) {
        float v = xb[h * Lq + l0 + tx];
        s += v; s2 += v * v;
    }
    __shared__ float rs_[16][17], r2_[16][17], mu_s[16], sg_s[16];
    rs_[ty][tx] = s; r2_[ty][tx] = s2;
    __syncthreads();
    if (ty == 0) {
        float a = 0.f, c = 0.f;
        #pragma unroll
        for (int i = 0; i < 16; ++i) { a += rs_[i][tx]; c += r2_[i][tx]; }
        float mu = a * (1.0f / Hq);
        float var = c * (1.0f / Hq) - mu * mu;
        mu_s[tx] = mu;
        sg_s[tx] = rsqrtf(var + 1e-5f);
    }
    __syncthreads();
    float mu = mu_s[tx], rs = sg_s[tx];
    float* zb = z + (size_t)b * Hq * Lq;
    for (int h = ty; h < Hq; h += 16) {
        float v = xb[h * Lq + l0 + tx];
        zb[h * Lq + l0 + tx] = (v - mu) * rs * lnw[h] + lnb[h];
    }
}

// ---------------------------------------------------------------------------
// delta GEMM (unchanged)
// ---------------------------------------------------------------------------
__global__ __launch_bounds__(256, 6)
void delta_kernel(const float* __restrict__ z, const float* __restrict__ pw,
                  float* __restrict__ buf) {
    __shared__ float Bs[64][68];
    int h = blockIdx.x, ct = blockIdx.y;
    int t = threadIdx.x;
    int dir = ct >> 1;
    int cc = t & 31, rb = (t >> 5) & 1, jg = t >> 6;
    int b = (ct & 1) * 2 + rb;
    const float* zb = z + ((size_t)b * Hq + h) * Lq;
    if (dir == 0) {
        #pragma unroll
        for (int f = 0; f < 4; ++f) {
            float4 v = *(const float4*)(zb + cc * 64 + 16 * jg + 4 * f);
            Bs[16*jg+4*f+0][rb*32+cc] = v.x;
            Bs[16*jg+4*f+1][rb*32+cc] = v.y;
            Bs[16*jg+4*f+2][rb*32+cc] = v.z;
            Bs[16*jg+4*f+3][rb*32+cc] = v.w;
        }
    } else {
        #pragma unroll
        for (int f = 0; f < 4; ++f) {
            float4 v = *(const float4*)(zb + 2044 - cc * 64 - 16 * jg - 4 * f);
            Bs[16*jg+4*f+3][rb*32+cc] = v.x;
            Bs[16*jg+4*f+2][rb*32+cc] = v.y;
            Bs[16*jg+4*f+1][rb*32+cc] = v.z;
            Bs[16*jg+4*f+0][rb*32+cc] = v.w;
        }
    }
    __syncthreads();
    int tx = t & 15, ty = t >> 4;
    float aR[4][4] = {}, aI[4][4] = {};
    const float* pwh = pw + (size_t)h * 65 * 128;
    #pragma unroll 4
    for (int kk = 0; kk < 64; ++kk) {
        int d = 63 - kk;
        const float4* pr = (const float4*)(pwh + (size_t)d * 128 + 8 * tx);
        float4 p0 = pr[0], p1 = pr[1];
        float4 bv = *(const float4*)&Bs[kk][4 * ty];
        float pc[4] = {p0.x, p0.z, p1.x, p1.z};
        float ps[4] = {p0.y, p0.w, p1.y, p1.w};
        #pragma unroll
        for (int rr = 0; rr < 4; ++rr) {
            #pragma unroll
            for (int q = 0; q < 4; ++q) {
                aR[rr][q] = fmaf(pc[rr], (&bv.x)[q], aR[rr][q]);
                aI[rr][q] = fmaf(ps[rr], (&bv.x)[q], aI[rr][q]);
            }
        }
    }
    #pragma unroll
    for (int q = 0; q < 4; ++q) {
        int colg = ct * 64 + 4 * ty + q;
        float* dst = buf + ((size_t)h * NCOL + colg) * 128 + 8 * tx;
        float4 v1, v2;
        v1.x = aR[0][q]; v1.y = aI[0][q]; v1.z = aR[1][q]; v1.w = aI[1][q];
        v2.x = aR[2][q]; v2.y = aI[2][q]; v2.z = aR[3][q]; v2.w = aI[3][q];
        *(float4*)dst = v1; *(float4*)(dst + 4) = v2;
    }
}

// ---------------------------------------------------------------------------
// inter-chunk scan (unchanged)
// ---------------------------------------------------------------------------
__global__ __launch_bounds__(256)
void cscan_kernel(const float* __restrict__ pw, float* __restrict__ buf) {
    int e = blockIdx.x * 4 + (threadIdx.x >> 6);
    int n = threadIdx.x & 63;
    int h = e >> 3, dir = (e >> 2) & 1, b = e & 3;
    float2 t64 = *(const float2*)(pw + (size_t)(h * 65 + 64) * 128 + 2 * n);
    float tc = t64.x, ts = t64.y;
    float sr = 0.f, si = 0.f;
    float2* p = (float2*)(buf + ((size_t)h * NCOL + dir * 128 + b * 32) * 128) + n;
    float2 d = p[0];
    for (int c = 0; c < NC; ++c) {
        float2 dn;
        if (c + 1 < NC) dn = p[(c + 1) * 64];
        float2 s; s.x = sr; s.y = si;
        p[c * 64] = s;
        float nr = fmaf(tc, sr, fmaf(-ts, si, d.x));
        float ni = fmaf(ts, sr, fmaf(tc, si, d.y));
        sr = nr; si = ni; d = dn;
    }
}

// ---------------------------------------------------------------------------
// Fused bidirectional Y GEMM + activation, physical coords, software-pipelined.
// Block = (h, bp): 64 rows (l in chunk) x 64 cols (2 batches x 32 chunks).
// 5 phases of BK=64:
//   p=0    : merged Toeplitz A[i][j] = (j<=i ? k0[i-j] : k1[j-i-1]), B = z
//   p=1,2  : G0 rows (w^{i+1}),  B = S0 scan col (b*32+ch)
//   p=3,4  : G1 rows (w^{63-i}), B = S1 scan col 128+(b*32+31-ch)
// Staging data for phase p+1 prefetched into regs during phase p compute.
// Epilogue: u = gelu(acc + D*z).
// ---------------------------------------------------------------------------
__global__ __launch_bounds__(256, 4)
void yact_kernel(const float* __restrict__ z, const float* __restrict__ pwT,
                 const float* __restrict__ a0, const float* __restrict__ b0,
                 const float* __restrict__ a1, const float* __restrict__ b1,
                 const float* __restrict__ kt, const float* __restrict__ buf,
                 const float* __restrict__ Dv, float* __restrict__ u) {
    __shared__ float As[64][68];
    __shared__ float Bs[64][68];
    __shared__ float ks0[64], ks1[64], as0_[64], bs0_[64], as1_[64], bs1_[64];
    int h = blockIdx.x, bp = blockIdx.y;
    int t = threadIdx.x;
    if (t < 64) {
        ks0[t]  = kt[((size_t)h * 2 + 0) * 64 + t];
        ks1[t]  = kt[((size_t)h * 2 + 1) * 64 + t];
        as0_[t] = a0[h * 64 + t]; bs0_[t] = b0[h * 64 + t];
        as1_[t] = a1[h * 64 + t]; bs1_[t] = b1[h * 64 + t];
    }
    int tx = t & 15, ty = t >> 4;        // microtile: rows 4tx+ii, cols 4ty+q
    int si = t & 63, kg = t >> 6;        // staging: lane si/cc, group kg
    int bS = 2 * bp + (si >> 5), ch = si & 31;
    const float* zb   = z + ((size_t)bS * Hq + h) * Lq + ch * 64;
    const float* bufh = buf + (size_t)h * NCOL * 128;
    const float* buf0 = bufh + (size_t)(bS * 32 + ch) * 128;
    const float* buf1 = bufh + (size_t)(128 + bS * 32 + (31 - ch)) * 128;
    const float* pwh  = pwT + (size_t)h * 64 * 132;
    float4 rB[4];
    float2 pv[8];
    #pragma unroll
    for (int f = 0; f < 4; ++f)
        rB[f] = *(const float4*)(zb + 16 * kg + 4 * f);
    float acc[4][4] = {};
    __syncthreads();
    for (int p = 0; p < 5; ++p) {
        // ---- write staging (from regs / LDS taps) ----
        if (p == 0) {
            #pragma unroll
            for (int q = 0; q < 16; ++q) {
                int kk = 16 * kg + q;
                int d = si - kk;
                As[kk][si] = (d >= 0) ? ks0[d] : ks1[-d - 1];
            }
        } else {
            const float* as_ = (p < 3) ? as0_ : as1_;
            const float* bs_ = (p < 3) ? bs0_ : bs1_;
            int pp = (p < 3) ? (p - 1) : (p - 3);
            #pragma unroll
            for (int q = 0; q < 16; ++q) {
                int j = q >> 1;
                int n = 32 * pp + 8 * kg + j;
                float vx = pv[j].x, vy = pv[j].y;
                As[16 * kg + q][si] = ((q & 1) == 0)
                    ? fmaf(as_[n], vx, bs_[n] * vy)
                    : fmaf(bs_[n], vx, -as_[n] * vy);
            }
        }
        #pragma unroll
        for (int f = 0; f < 4; ++f) {
            Bs[16*kg + 4*f + 0][si] = rB[f].x;
            Bs[16*kg + 4*f + 1][si] = rB[f].y;
            Bs[16*kg + 4*f + 2][si] = rB[f].z;
            Bs[16*kg + 4*f + 3][si] = rB[f].w;
        }
        __syncthreads();
        // ---- prefetch next phase into regs (hidden under compute) ----
        if (p < 4) {
            int pn = p + 1;
            int pp = (pn < 3) ? (pn - 1) : (pn - 3);
            const float* src = (pn < 3) ? buf0 : buf1;
            #pragma unroll
            for (int f = 0; f < 4; ++f)
                rB[f] = *(const float4*)(src + 64 * pp + 16 * kg + 4 * f);
            int dsel = (pn < 3) ? (si + 1) : (63 - si);
            #pragma unroll
            for (int j = 0; j < 8; ++j) {
                int n = 32 * pp + 8 * kg + j;
                pv[j] = *(const float2*)(pwh + (size_t)n * 132 + 2 * dsel);
            }
        }
        // ---- compute ----
        #pragma unroll 8
        for (int kk = 0; kk < 64; ++kk) {
            float4 av = *(const float4*)&As[kk][4 * tx];
            float4 bv = *(const float4*)&Bs[kk][4 * ty];
            #pragma unroll
            for (int ii = 0; ii < 4; ++ii) {
                float a = (&av.x)[ii];
                acc[ii][0] = fmaf(a, bv.x, acc[ii][0]);
                acc[ii][1] = fmaf(a, bv.y, acc[ii][1]);
                acc[ii][2] = fmaf(a, bv.z, acc[ii][2]);
                acc[ii][3] = fmaf(a, bv.w, acc[ii][3]);
            }
        }
        __syncthreads();
    }
    float dv = Dv[h];
    #pragma unroll
    for (int q = 0; q < 4; ++q) {
        int cc2 = 4 * ty + q;
        int b2 = 2 * bp + (cc2 >> 5), ch2 = cc2 & 31;
        size_t base = ((size_t)b2 * Hq + h) * Lq + ch2 * 64 + 4 * tx;
        float4 zr = *(const float4*)(z + base);
        float vv[4];
        vv[0] = acc[0][q] + dv * zr.x;
        vv[1] = acc[1][q] + dv * zr.y;
        vv[2] = acc[2][q] + dv * zr.z;
        vv[3] = acc[3][q] + dv * zr.w;
        #pragma unroll
        for (int i = 0; i < 4; ++i) {
            float v = vv[i];
            float tt = tanhf(0.7978845608028654f * (v + 0.044715f * v * v * v));
            vv[i] = 0.5f * v * (1.0f + tt);
        }
        float4 r; r.x = vv[0]; r.y = vv[1]; r.z = vv[2]; r.w = vv[3];
        *(float4*)(u + base) = r;
    }
}

// ---------------------------------------------------------------------------
// Phase 5: out = bias + x + W@u. (unchanged)
// ---------------------------------------------------------------------------
__global__ __launch_bounds__(512, 4)
void gemm_kernel(const float* __restrict__ u, const float* __restrict__ W,
                 const float* __restrict__ bias, const float* __restrict__ x,
                 float* __restrict__ out) {
    int l0 = blockIdx.x * 64;
    int o0 = blockIdx.y * 128;
    int b  = blockIdx.z;
    int tid = threadIdx.x;
    __shared__ float Ws[2][32][132];
    __shared__ float Us[2][32][68];
    const float* ub = u + (size_t)b * Hq * Lq;
    float acc[4][4] = {};
    int wo = tid >> 4, wl = tid & 15;
    int sj = tid & 31, so = tid >> 5;
    int sl = tid & 63, sk = tid >> 6;
    float wreg[8], ureg[4];
    #pragma unroll
    for (int r = 0; r < 8; ++r) wreg[r] = W[(size_t)(o0 + so + 16*r) * Hq + sj];
    #pragma unroll
    for (int r = 0; r < 4; ++r) ureg[r] = ub[(size_t)(4*sk + r) * Lq + l0 + sl];
    #pragma unroll
    for (int r = 0; r < 8; ++r) Ws[0][sj][so + 16*r] = wreg[r];
    #pragma unroll
    for (int r = 0; r < 4; ++r) Us[0][4*sk + r][sl] = ureg[r];
    __syncthreads();
    for (int t = 0; t < Hq / 32; ++t) {
        int cur = t & 1;
        if (t < 15) {
            int k0 = (t + 1) * 32;
            #pragma unroll
            for (int r = 0; r < 8; ++r)
                wreg[r] = W[(size_t)(o0 + so + 16*r) * Hq + k0 + sj];
            #pragma unroll
            for (int r = 0; r < 4; ++r)
                ureg[r] = ub[(size_t)(k0 + 4*sk + r) * Lq + l0 + sl];
        }
        #pragma unroll 8
        for (int j = 0; j < 32; ++j) {
            float4 av = *(const float4*)&Ws[cur][j][4 * wo];
            float4 bv = *(const float4*)&Us[cur][j][4 * wl];
            #pragma unroll
            for (int io = 0; io < 4; ++io) {
                float a = (&av.x)[io];
                acc[io][0] = fmaf(a, bv.x, acc[io][0]);
                acc[io][1] = fmaf(a, bv.y, acc[io][1]);
                acc[io][2] = fmaf(a, bv.z, acc[io][2]);
                acc[io][3] = fmaf(a, bv.w, acc[io][3]);
            }
        }
        if (t < 15) {
            int nxt = cur ^ 1;
            #pragma unroll
            for (int r = 0; r < 8; ++r) Ws[nxt][sj][so + 16*r] = wreg[r];
            #pragma unroll
            for (int r = 0; r < 4; ++r) Us[nxt][4*sk + r][sl] = ureg[r];
        }
        __syncthreads();
    }
    #pragma unroll
    for (int io = 0; io < 4; ++io) {
        int o = o0 + 4 * wo + io;
        float bo = bias[o];
        size_t base = ((size_t)b * Hq + o) * Lq + l0 + 4 * wl;
        const float4 xr = *(const float4*)(x + base);
        float4 r;
        r.x = acc[io][0] + bo + xr.x;
        r.y = acc[io][1] + bo + xr.y;
        r.z = acc[io][2] + bo + xr.z;
        r.w = acc[io][3] + bo + xr.w;
        *(float4*)(out + base) = r;
    }
}

// ---------------------------------------------------------------------------
extern "C" void kernel_launch(void* const* d_in, const int* in_sizes, int n_in,
                              void* d_out, int out_size, void* d_ws, size_t ws_size,
                              hipStream_t stream) {
    (void)in_sizes; (void)n_in; (void)out_size; (void)ws_size;
    const float* x          = (const float*)d_in[0];
    const float* ln_w       = (const float*)d_in[1];
    const float* ln_b       = (const float*)d_in[2];
    const float* log_dt     = (const float*)d_in[3];
    const float* log_A_real = (const float*)d_in[4];
    const float* A_imag     = (const float*)d_in[5];
    const float* B_re       = (const float*)d_in[6];
    const float* B_im       = (const float*)d_in[7];
    const float* C_re       = (const float*)d_in[8];
    const float* C_im       = (const float*)d_in[9];
    const float* Dv         = (const float*)d_in[10];
    const float* W          = (const float*)d_in[11];
    const float* b_out      = (const float*)d_in[12];
    float* out = (float*)d_out;
    float* ws  = (float*)d_ws;

    const size_t BHL = (size_t)Bq * Hq * Lq;
    float* a0  = ws;
    float* b0  = ws + (size_t)PARAM;
    float* a1  = ws + 2 * (size_t)PARAM;
    float* b1  = ws + 3 * (size_t)PARAM;
    float* kt  = ws + 4 * (size_t)PARAM;
    float* pw  = ws + 6 * (size_t)PARAM;           // 512*65*128 = 130*PARAM
    float* pwT = ws + 136 * (size_t)PARAM;         // 512*64*132 = 132*PARAM
    float* z   = ws + 268 * (size_t)PARAM;
    float* u   = z  + BHL;
    float* buf = u + BHL;                          // 512*256*128 = 67 MB

    prep_kernel<<<PARAM / 256, 256, 0, stream>>>(log_dt, log_A_real, A_imag,
                                                 B_re, B_im, C_re, C_im,
                                                 a0, b0, a1, b1, pw, pwT);
    ln_kernel<<<Bq * (Lq / 16), 256, 0, stream>>>(x, ln_w, ln_b, z);
    ktap_kernel<<<Hq, 128, 0, stream>>>(pw, a0, b0, a1, b1, kt);
    delta_kernel<<<dim3(Hq, 4), 256, 0, stream>>>(z, pw, buf);
    cscan_kernel<<<Bq * Hq * 2 / 4, 256, 0, stream>>>(pw, buf);
    yact_kernel<<<dim3(Hq, 2), 256, 0, stream>>>(z, pwT, a0, b0, a1, b1,
                                                 kt, buf, Dv, u);
    gemm_kernel<<<dim3(Lq / 64, Hq / 128, Bq), 512, 0, stream>>>(u, W, b_out, x, out);
}